// Round 2
// baseline (1128.876 us; speedup 1.0000x reference)
//
#include <hip/hip_runtime.h>

#define T_FRAMES 32768
#define ROWF 1629          // 543*3 floats per frame
#define NSEG 512
#define NVAL 122           // 42 hand + 80 lips values per frame
#define PADI 16            // accumulator padding: one per 64B cacheline

// -------------------------------------------------------------------------
// K1: keep flags (one frame per wave, hand region only ~29 MB total) + the
// compaction scan, executed by the LAST block to finish (device-scope fence
// + done-counter; deadlock-free, no co-residency assumption). Replaces the
// former k1+k2 pair -> one dispatch.
// -------------------------------------------------------------------------
__global__ __launch_bounds__(1024) void k1_keep_scan(
    const float* __restrict__ frames, int* __restrict__ keep,
    int* __restrict__ kept_t, int* __restrict__ Sp, int* __restrict__ ctl) {
  int tid = threadIdx.x, lane = tid & 63, wid = tid >> 6;
  int t = blockIdx.x * 16 + wid;              // 2048 blocks x 16 frames
  const float* f = frames + (size_t)t * ROWF;
  float s = 0.0f;
  if (lane < 42) {
    int base = (lane < 21) ? (468 + lane) : (522 + (lane - 21));
    float x = f[base * 3];
    float y = f[base * 3 + 1];
    float ax = (lane < 21) ? x : 1.0f - x;    // lh:[x,1-y]  rh:[1-x,1-y]
    float ay = 1.0f - y;
    ax = (ax == ax) ? ax : 0.0f;
    ay = (ay == ay) ? ay : 0.0f;
    s = ax + ay;                              // terms nonnegative; ==0 iff all-NaN
  }
  #pragma unroll
  for (int off = 32; off > 0; off >>= 1) s += __shfl_down(s, off);
  if (lane == 0) keep[t] = (s != 0.0f) ? 1 : 0;

  // ---- last-block-done: run the scan inline ----
  __shared__ int is_last;
  __threadfence();                            // release keep[] writes
  __syncthreads();
  if (tid == 0) is_last = (atomicAdd(&ctl[0], 1) == (int)gridDim.x - 1);
  __syncthreads();
  if (!is_last) return;
  __threadfence();                            // acquire all blocks' keep[]

  __shared__ int wsum[16];
  const int PER = T_FRAMES / 1024;            // 32
  int base = tid * PER;
  int fl[PER];
  int local = 0;
  #pragma unroll
  for (int k = 0; k < PER; ++k) { fl[k] = keep[base + k]; local += fl[k]; }
  int scan = local;
  #pragma unroll
  for (int off = 1; off < 64; off <<= 1) {
    int n = __shfl_up(scan, off);
    if (lane >= off) scan += n;
  }
  if (lane == 63) wsum[wid] = scan;
  __syncthreads();
  if (tid < 16) {
    int v = wsum[tid];
    #pragma unroll
    for (int off = 1; off < 16; off <<= 1) {
      int n = __shfl_up(v, off);
      if (tid >= off) v += n;
    }
    wsum[tid] = v;
  }
  __syncthreads();
  int excl = ((wid == 0) ? 0 : wsum[wid - 1]) + (scan - local);
  #pragma unroll
  for (int k = 0; k < PER; ++k) {
    if (fl[k]) kept_t[excl++] = base + k;
  }
  if (tid == 1023) Sp[0] = wsum[15];
}

// -------------------------------------------------------------------------
// K3: one block (16 waves) per segment; exclusive ownership of kept ranks
// [lo,hi) -> no cross-block atomics for segment sums. Single gather pass,
// register accumulation, LDS reduce, hand means written directly. Lips
// finalize (former k4) runs in the LAST block to finish, reading the
// L2-resident seg_ls/seg_lc/seg_n + global totals -> one dispatch.
// -------------------------------------------------------------------------
__global__ __launch_bounds__(1024) void k3_seg(
    const float* __restrict__ frames, const int* __restrict__ lips_idx,
    const int* __restrict__ kept_t, const int* __restrict__ Sp,
    float* __restrict__ out, int out_size,
    float* __restrict__ seg_ls, int* __restrict__ seg_lc,
    int* __restrict__ seg_n, float* __restrict__ tot_s,
    int* __restrict__ tot_c, int* __restrict__ ctl) {
  __shared__ int seglist[72];                 // cnt <= 64 (+1 for rank S-1)
  __shared__ float h_s[42];
  __shared__ float l_s[80];
  __shared__ int   l_c[80];
  int tid = threadIdx.x, lane = tid & 63, wid = tid >> 6;
  int seg = blockIdx.x;
  int S = Sp[0];
  long long M = (long long)S - 1; if (M < 0) M = 0;
  int lo = (int)(((long long)seg * M) >> 9);
  int hi = (int)(((long long)(seg + 1) * M) >> 9);
  int cnt = hi - lo;
  // rank S-1 is in no segment (JAX OOB-drop) but IS in the lips column mean
  int loadN = cnt + ((seg == NSEG - 1 && S >= 2) ? 1 : 0);

  if (tid < 42) h_s[tid] = 0.0f;
  if (tid < 80) { l_s[tid] = 0.0f; l_c[tid] = 0; }
  if (tid < loadN) seglist[tid] = kept_t[lo + tid];
  __syncthreads();

  int idx1 = 0, idx2 = 0;
  if (lane >= 42) idx1 = lips_idx[lane - 42];
  if (lane < 18)  idx2 = lips_idx[22 + lane];

  float ahx = 0.0f, ahy = 0.0f;               // hand acc (lane<21)
  float a1x = 0.0f, a1y = 0.0f; int c1x = 0, c1y = 0;  // lips set1 (lane>=42)
  float a2x = 0.0f, a2y = 0.0f; int c2x = 0, c2y = 0;  // lips set2 (lane<18)

  for (int k = wid; k < cnt; k += 16) {
    const float* f = frames + (size_t)seglist[k] * ROWF;
    int o1;
    if (lane < 21)      o1 = (468 + lane) * 3;
    else if (lane < 42) o1 = (522 + (lane - 21)) * 3;
    else                o1 = idx1 * 3;
    float x1 = f[o1], y1 = f[o1 + 1];
    float x2 = 0.0f, y2 = 0.0f;
    if (lane < 18) { int o2 = idx2 * 3; x2 = f[o2]; y2 = f[o2 + 1]; }

    // hand transform (lanes<42): lh -> (x,1-y), rh -> (1-x,1-y), nan->0
    float ax = (lane < 21) ? x1 : 1.0f - x1;
    float ay = 1.0f - y1;
    ax = (ax == ax) ? ax : 0.0f;
    ay = (ay == ay) ? ay : 0.0f;
    float bx = __shfl(ax, lane + 21);         // lane j pulls rh pair j
    float by = __shfl(ay, lane + 21);
    if (lane < 21) { ahx += ax + bx; ahy += ay + by; }
    if (lane >= 42) {
      if (x1 == x1) { a1x += x1; c1x++; }
      if (y1 == y1) { a1y += y1; c1y++; }
    }
    if (lane < 18) {
      if (x2 == x2) { a2x += x2; c2x++; }
      if (y2 == y2) { a2y += y2; c2y++; }
    }
  }

  // block reduce: 16 waves into LDS (16-way atomic contention max)
  if (lane < 21) { atomicAdd(&h_s[2 * lane], ahx); atomicAdd(&h_s[2 * lane + 1], ahy); }
  if (lane >= 42) {
    int j = lane - 42;
    atomicAdd(&l_s[2 * j], a1x); atomicAdd(&l_s[2 * j + 1], a1y);
    atomicAdd(&l_c[2 * j], c1x); atomicAdd(&l_c[2 * j + 1], c1y);
  }
  if (lane < 18) {
    int j = 22 + lane;
    atomicAdd(&l_s[2 * j], a2x); atomicAdd(&l_s[2 * j + 1], a2y);
    atomicAdd(&l_c[2 * j], c2x); atomicAdd(&l_c[2 * j + 1], c2y);
  }
  __syncthreads();

  if (tid < 42) {
    float v = cnt ? h_s[tid] / (float)cnt : 0.0f;
    int o = seg * NVAL + tid;
    if (o < out_size) out[o] = v;             // hand means final here
  }
  if (tid < 80) {
    seg_ls[seg * 80 + tid] = l_s[tid];
    seg_lc[seg * 80 + tid] = l_c[tid];
    atomicAdd(&tot_s[tid * PADI], l_s[tid]);  // padded: 1 accum / cacheline
    atomicAdd(&tot_c[tid * PADI], l_c[tid]);
  }
  if (tid == 0) seg_n[seg] = cnt;

  // rank S-1 -> global lips totals only
  if (seg == NSEG - 1 && S >= 2 && wid == 0 && lane < 40) {
    const float* f = frames + (size_t)seglist[cnt] * ROWF;
    int idx = lips_idx[lane];
    float x = f[idx * 3], y = f[idx * 3 + 1];
    if (x == x) { atomicAdd(&tot_s[(2 * lane) * PADI], x);
                  atomicAdd(&tot_c[(2 * lane) * PADI], 1); }
    if (y == y) { atomicAdd(&tot_s[(2 * lane + 1) * PADI], y);
                  atomicAdd(&tot_c[(2 * lane + 1) * PADI], 1); }
  }

  // ---- last-block-done: lips finalize (former k4) ----
  __shared__ int last2;
  __threadfence();                            // release seg_*/tot_* writes
  __syncthreads();
  if (tid == 0) last2 = (atomicAdd(&ctl[16], 1) == NSEG - 1);
  __syncthreads();
  if (!last2) return;
  __threadfence();                            // acquire all blocks' writes

  for (int i = tid; i < NSEG * 80; i += 1024) {
    int sg = i / 80, w = i - sg * 80;
    int tc = tot_c[w * PADI];
    float cm = tc ? tot_s[w * PADI] / (float)tc : 0.0f;
    int n = seg_n[sg];
    float v = 0.0f;
    if (n) {
      int c = seg_lc[sg * 80 + w];
      v = (seg_ls[sg * 80 + w] + (float)(n - c) * cm) / (float)n;
    }
    int o = sg * NVAL + 42 + w;
    if (o < out_size) out[o] = v;
  }
}

// -------------------------------------------------------------------------
extern "C" void kernel_launch(void* const* d_in, const int* in_sizes, int n_in,
                              void* d_out, int out_size, void* d_ws, size_t ws_size,
                              hipStream_t stream) {
  const float* frames = (const float*)d_in[0];
  const int* lips_idx = (const int*)d_in[1];
  float* out = (float*)d_out;

  char* ws = (char*)d_ws;
  int* keep      = (int*)(ws);                     // 131072 B
  int* kept_t    = (int*)(ws + 131072);            // 131072 B
  int* Sp        = (int*)(ws + 262144);            // 64 B
  int* ctl       = (int*)(ws + 262208);            // 128 B: done1@[0], done2@[16]
  float* tot_s   = (float*)(ws + 262336);          // 80 * 64B = 5120 B
  int* tot_c     = (int*)(ws + 267456);            // 80 * 64B = 5120 B
  float* seg_ls  = (float*)(ws + 272576);          // 512*80*4 = 163840 B
  int* seg_lc    = (int*)(ws + 436416);            // 163840 B
  int* seg_n     = (int*)(ws + 600256);            // 2048 B

  // ctl + tot_s + tot_c must start at zero (ws is poisoned before every
  // call); they are contiguous -> one 10368 B memset
  hipMemsetAsync((void*)ctl, 0, 10368, stream);

  k1_keep_scan<<<2048, 1024, 0, stream>>>(frames, keep, kept_t, Sp, ctl);
  k3_seg<<<NSEG, 1024, 0, stream>>>(frames, lips_idx, kept_t, Sp, out, out_size,
                                    seg_ls, seg_lc, seg_n, tot_s, tot_c, ctl);
}

// Round 4
// 315.789 us; speedup vs baseline: 3.5748x; 3.5748x over previous
//
#include <hip/hip_runtime.h>

#define T_FRAMES 32768
#define ROWF 1629          // 543*3 floats per frame
#define NSEG 512
#define NVAL 122           // 42 hand + 80 lips values per frame

// -------------------------------------------------------------------------
// DETERMINISM NOTE (R3 post-mortem): a prior version reduced with LDS/global
// float atomicAdd and intermittently failed the post-timing check with an
// error of exactly one wave-partial (~0.0625) lost from one segment mean.
// This version has ZERO atomics: all reductions are fixed-order trees, so
// every call is bitwise identical. It also reads no workspace byte it did
// not write this call (no memset needed).
// R2 post-mortem: do NOT fuse kernels via last-block-done + __threadfence()
// — per-wave device fences on gfx950 (non-coherent XCD L2s) serialized to
// 640 us. Kernel boundaries are the cheap device-scope fence.
// -------------------------------------------------------------------------

// K1: keep flags only. One frame per wave; reads ONLY the hand region.
// keep==0 iff all hand entries NaN (contributions nonnegative).
__global__ __launch_bounds__(256) void k1_keep(const float* __restrict__ frames,
                                               int* __restrict__ keep) {
  int lane = threadIdx.x & 63;
  int wid = threadIdx.x >> 6;                 // 0..3
  int t = blockIdx.x * 4 + wid;
  const float* f = frames + (size_t)t * ROWF;
  float s = 0.0f;
  if (lane < 42) {
    int base = (lane < 21) ? (468 + lane) : (522 + (lane - 21));
    float x = f[base * 3];
    float y = f[base * 3 + 1];
    float ax = (lane < 21) ? x : 1.0f - x;    // lh:[x,1-y]  rh:[1-x,1-y]
    float ay = 1.0f - y;
    ax = (ax == ax) ? ax : 0.0f;
    ay = (ay == ay) ? ay : 0.0f;
    s = ax + ay;
  }
  #pragma unroll
  for (int off = 32; off > 0; off >>= 1) s += __shfl_down(s, off);
  if (lane == 0) keep[t] = (s != 0.0f) ? 1 : 0;
}

// K2: single-block prefix scan of keep[] -> compacted kept_t[], total S.
__global__ __launch_bounds__(1024) void k2_scan(const int* __restrict__ keep,
                                                int* __restrict__ kept_t,
                                                int* __restrict__ Sp) {
  __shared__ int wsum[16];
  int tid = threadIdx.x;
  const int PER = T_FRAMES / 1024;            // 32
  int base = tid * PER;
  int fl[PER];
  int local = 0;
  #pragma unroll
  for (int k = 0; k < PER; ++k) { fl[k] = keep[base + k]; local += fl[k]; }

  int lane = tid & 63, wid = tid >> 6;
  int scan = local;
  #pragma unroll
  for (int off = 1; off < 64; off <<= 1) {
    int n = __shfl_up(scan, off);
    if (lane >= off) scan += n;
  }
  if (lane == 63) wsum[wid] = scan;
  __syncthreads();
  if (tid < 16) {
    int v = wsum[tid];
    #pragma unroll
    for (int off = 1; off < 16; off <<= 1) {
      int n = __shfl_up(v, off);
      if (tid >= off) v += n;
    }
    wsum[tid] = v;
  }
  __syncthreads();
  int excl = ((wid == 0) ? 0 : wsum[wid - 1]) + (scan - local);
  #pragma unroll
  for (int k = 0; k < PER; ++k) {
    if (fl[k]) kept_t[excl++] = base + k;
  }
  if (tid == 1023) Sp[0] = wsum[15];
}

// K3: one block (16 waves) per segment; exclusive ownership of kept ranks
// [lo,hi) -> no cross-block reduction at all. Single gather pass over
// frames; per-wave register accumulation; fixed-order LDS tree reduce
// (deterministic); hand means written directly, lips finite-sums/counts
// stored per-segment for K4.
// Lane roles: [0,21) lh-pair j=lane; [21,42) rh-pair j=lane-21;
// [42,64) lips-pair j=lane-42; second set: lane<18 lips-pair j=22+lane.
__global__ __launch_bounds__(1024) void k3_seg(
    const float* __restrict__ frames, const int* __restrict__ lips_idx,
    const int* __restrict__ kept_t, const int* __restrict__ Sp,
    float* __restrict__ out, int out_size,
    float* __restrict__ seg_ls, int* __restrict__ seg_lc,
    int* __restrict__ seg_n) {
  __shared__ int seglist[64];                 // cnt <= ceil((S-1)/512) <= 64
  __shared__ float hp[16][42];
  __shared__ float lp[16][80];
  __shared__ int   cp[16][80];
  int tid = threadIdx.x, lane = tid & 63, wid = tid >> 6;
  int seg = blockIdx.x;
  int S = Sp[0];
  long long M = (long long)S - 1; if (M < 0) M = 0;
  int lo = (int)(((long long)seg * M) >> 9);
  int hi = (int)(((long long)(seg + 1) * M) >> 9);
  int cnt = hi - lo;                          // rank S-1 handled in K4

  if (tid < cnt) seglist[tid] = kept_t[lo + tid];
  __syncthreads();

  int idx1 = 0, idx2 = 0;
  if (lane >= 42) idx1 = lips_idx[lane - 42];
  if (lane < 18)  idx2 = lips_idx[22 + lane];

  float ahx = 0.0f, ahy = 0.0f;               // hand acc (lane<21)
  float a1x = 0.0f, a1y = 0.0f; int c1x = 0, c1y = 0;  // lips set1 (lane>=42)
  float a2x = 0.0f, a2y = 0.0f; int c2x = 0, c2y = 0;  // lips set2 (lane<18)

  for (int k = wid; k < cnt; k += 16) {
    const float* f = frames + (size_t)seglist[k] * ROWF;
    int o1;
    if (lane < 21)      o1 = (468 + lane) * 3;
    else if (lane < 42) o1 = (522 + (lane - 21)) * 3;
    else                o1 = idx1 * 3;
    float x1 = f[o1], y1 = f[o1 + 1];
    float x2 = 0.0f, y2 = 0.0f;
    if (lane < 18) { int o2 = idx2 * 3; x2 = f[o2]; y2 = f[o2 + 1]; }

    // hand transform (lanes<42): lh -> (x,1-y), rh -> (1-x,1-y), nan->0
    float ax = (lane < 21) ? x1 : 1.0f - x1;
    float ay = 1.0f - y1;
    ax = (ax == ax) ? ax : 0.0f;
    ay = (ay == ay) ? ay : 0.0f;
    float bx = __shfl(ax, lane + 21);         // lane j pulls rh pair j
    float by = __shfl(ay, lane + 21);
    if (lane < 21) { ahx += ax + bx; ahy += ay + by; }
    if (lane >= 42) {
      if (x1 == x1) { a1x += x1; c1x++; }
      if (y1 == y1) { a1y += y1; c1y++; }
    }
    if (lane < 18) {
      if (x2 == x2) { a2x += x2; c2x++; }
      if (y2 == y2) { a2y += y2; c2y++; }
    }
  }

  // per-wave partials -> LDS (no atomics)
  if (lane < 21) { hp[wid][2 * lane] = ahx; hp[wid][2 * lane + 1] = ahy; }
  if (lane >= 42) {
    int j = lane - 42;
    lp[wid][2 * j] = a1x; lp[wid][2 * j + 1] = a1y;
    cp[wid][2 * j] = c1x; cp[wid][2 * j + 1] = c1y;
  }
  if (lane < 18) {
    int j = 22 + lane;
    lp[wid][2 * j] = a2x; lp[wid][2 * j + 1] = a2y;
    cp[wid][2 * j] = c2x; cp[wid][2 * j + 1] = c2y;
  }
  __syncthreads();

  // fixed-order 16-way combine (bitwise deterministic)
  if (tid < 42) {
    float s = 0.0f;
    #pragma unroll
    for (int w = 0; w < 16; ++w) s += hp[w][tid];
    float v = cnt ? s / (float)cnt : 0.0f;
    int o = seg * NVAL + tid;
    if (o < out_size) out[o] = v;             // hand means final here
  }
  if (tid < 80) {
    float s = 0.0f; int c = 0;
    #pragma unroll
    for (int w = 0; w < 16; ++w) { s += lp[w][tid]; c += cp[w][tid]; }
    seg_ls[seg * 80 + tid] = s;
    seg_lc[seg * 80 + tid] = c;
  }
  if (tid == 0) seg_n[seg] = cnt;
}

// K4: single block. Deterministically derives the lips column means cm[80]
// from seg_ls/seg_lc (8 fixed groups of 64 segments) + the rank S-1 frame
// (in no segment per JAX OOB-drop, but in the column mean), then writes all
// 512*80 lips outputs: mean = (sum_finite + (n - c_finite)*cm) / n.
__global__ __launch_bounds__(1024) void k4_final(
    const float* __restrict__ frames, const int* __restrict__ lips_idx,
    const int* __restrict__ kept_t, const int* __restrict__ Sp,
    const float* __restrict__ seg_ls, const int* __restrict__ seg_lc,
    const int* __restrict__ seg_n, float* __restrict__ out, int out_size) {
  __shared__ float sp[8][80];
  __shared__ int   scp[8][80];
  __shared__ float cmv[80];
  int tid = threadIdx.x;
  int S = Sp[0];

  if (tid < 640) {
    int g = tid / 80, w = tid - g * 80;
    float s = 0.0f; int c = 0;
    for (int sg = g * 64; sg < g * 64 + 64; ++sg) {
      s += seg_ls[sg * 80 + w];
      c += seg_lc[sg * 80 + w];
    }
    sp[g][w] = s; scp[g][w] = c;
  }
  __syncthreads();
  if (tid < 80) {
    float s = 0.0f; int c = 0;
    #pragma unroll
    for (int g = 0; g < 8; ++g) { s += sp[g][tid]; c += scp[g][tid]; }
    if (S >= 1) {                             // rank S-1 lips contribution
      int j = tid >> 1, ch = tid & 1;
      float x = frames[(size_t)kept_t[S - 1] * ROWF + lips_idx[j] * 3 + ch];
      if (x == x) { s += x; c += 1; }
    }
    cmv[tid] = c ? s / (float)c : 0.0f;
  }
  __syncthreads();

  for (int i = tid; i < NSEG * 80; i += 1024) {
    int sg = i / 80, w = i - sg * 80;
    int n = seg_n[sg];
    float v = 0.0f;
    if (n) {
      int c = seg_lc[sg * 80 + w];
      v = (seg_ls[sg * 80 + w] + (float)(n - c) * cmv[w]) / (float)n;
    }
    int o = sg * NVAL + 42 + w;
    if (o < out_size) out[o] = v;
  }
}

// -------------------------------------------------------------------------
extern "C" void kernel_launch(void* const* d_in, const int* in_sizes, int n_in,
                              void* d_out, int out_size, void* d_ws, size_t ws_size,
                              hipStream_t stream) {
  const float* frames = (const float*)d_in[0];
  const int* lips_idx = (const int*)d_in[1];
  float* out = (float*)d_out;

  char* ws = (char*)d_ws;
  int* keep      = (int*)(ws);                     // 131072 B
  int* kept_t    = (int*)(ws + 131072);            // 131072 B
  int* Sp        = (int*)(ws + 262144);            // 64 B
  float* seg_ls  = (float*)(ws + 262208);          // 512*80*4 = 163840 B
  int* seg_lc    = (int*)(ws + 426048);            // 163840 B
  int* seg_n     = (int*)(ws + 589888);            // 2048 B
  // every ws byte read this call is written this call -> no memset needed

  k1_keep<<<8192, 256, 0, stream>>>(frames, keep);
  k2_scan<<<1, 1024, 0, stream>>>(keep, kept_t, Sp);
  k3_seg<<<NSEG, 1024, 0, stream>>>(frames, lips_idx, kept_t, Sp, out, out_size,
                                    seg_ls, seg_lc, seg_n);
  k4_final<<<1, 1024, 0, stream>>>(frames, lips_idx, kept_t, Sp,
                                   seg_ls, seg_lc, seg_n, out, out_size);
}